// Round 1
// baseline (423.471 us; speedup 1.0000x reference)
//
#include <hip/hip_runtime.h>

#define FWHT_SIZE 4096
#define TPB 256

// FWHT over 16 register-resident values, distances 1,2,4,8 (Sylvester order).
__device__ __forceinline__ void fwht16(float a[16]) {
#pragma unroll
    for (int h = 1; h < 16; h <<= 1) {
#pragma unroll
        for (int i = 0; i < 16; i += 2 * h) {
#pragma unroll
            for (int j = i; j < i + h; ++j) {
                float u = a[j];
                float v = a[j + h];
                a[j]     = u + v;
                a[j + h] = u - v;
            }
        }
    }
}

// LDS address map: A(i) = i + (i>>4) + (i>>8)  -> breaks stride-16 and
// stride-256 bank alignment; all access patterns land at ~2-way conflicts
// (free on gfx950, m136). Max address A(4095) = 4365.
#define LDS_WORDS 4368

__global__ __launch_bounds__(TPB, 8) void fwht_rows_kernel(
        const float* __restrict__ x,
        const float* __restrict__ s,
        float* __restrict__ out) {
    __shared__ float lds[LDS_WORDS];

    const int row = blockIdx.x;
    const int t   = threadIdx.x;
    const float* xr = x   + (size_t)row * FWHT_SIZE;
    float*       orw = out + (size_t)row * FWHT_SIZE;

    float a[16];

    // ---- Pass A: bits 0..3. Thread t holds contiguous x[16t .. 16t+15].
    {
        const float4* xv = (const float4*)(xr + 16 * t);
        const float4* sv = (const float4*)(s + 16 * t);
#pragma unroll
        for (int j = 0; j < 4; ++j) {
            float4 xx = xv[j];
            float4 ss = sv[j];
            a[4 * j + 0] = xx.x * ss.x;
            a[4 * j + 1] = xx.y * ss.y;
            a[4 * j + 2] = xx.z * ss.z;
            a[4 * j + 3] = xx.w * ss.w;
        }
    }
    fwht16(a);

    // ---- Exchange 1: write A(16t+j) = 17t + (t>>4) + j  (contiguous per thread)
    {
        const int base = 17 * t + (t >> 4);
#pragma unroll
        for (int j = 0; j < 16; ++j) lds[base + j] = a[j];
    }
    __syncthreads();

    const int hi = t >> 4;   // i2 in pass B, i1 in pass C
    const int lo = t & 15;   // i0

    // ---- Pass B: bits 4..7. idx = 256*hi + 16*k + lo ; A(idx) = 273*hi + 17*k + lo
    {
        const int base = 273 * hi + lo;
#pragma unroll
        for (int k = 0; k < 16; ++k) a[k] = lds[base + 17 * k];
    }
    fwht16(a);
    // write back to the same cells (only this thread touched them: no barrier needed
    // between the read above and this write)
    {
        const int base = 273 * hi + lo;
#pragma unroll
        for (int k = 0; k < 16; ++k) lds[base + 17 * k] = a[k];
    }
    __syncthreads();

    // ---- Pass C: bits 8..11. idx = 256*k + t ; A(idx) = 273*k + 17*hi + lo
    {
        const int base = 17 * hi + lo;
#pragma unroll
        for (int k = 0; k < 16; ++k) a[k] = lds[base + 273 * k];
    }
    fwht16(a);

    // ---- Scale and store: out[256*k + t]  (fully coalesced, 1 KiB per instr per block)
    const float scale = 0.015625f;  // 1/sqrt(4096)
#pragma unroll
    for (int k = 0; k < 16; ++k) {
        orw[256 * k + t] = a[k] * scale;
    }
}

extern "C" void kernel_launch(void* const* d_in, const int* in_sizes, int n_in,
                              void* d_out, int out_size, void* d_ws, size_t ws_size,
                              hipStream_t stream) {
    const float* x = (const float*)d_in[0];
    const float* s = (const float*)d_in[1];
    float* out = (float*)d_out;
    const int rows = in_sizes[0] / FWHT_SIZE;  // 16384
    fwht_rows_kernel<<<rows, TPB, 0, stream>>>(x, s, out);
}

// Round 3
// 422.019 us; speedup vs baseline: 1.0034x; 1.0034x over previous
//
#include <hip/hip_runtime.h>

#define FWHT_N 4096
#define TPB 256

// FWHT over 16 register-resident values, distances 1,2,4,8 (Sylvester order).
// Register bit m_b maps to a global index bit; butterfly stages over disjoint
// bits commute, so splitting the 12 bits into three groups of 4 (any order)
// reproduces H = H2^{(x)12} exactly.
__device__ __forceinline__ void fwht16(float a[16]) {
#pragma unroll
    for (int h = 1; h < 16; h <<= 1) {
#pragma unroll
        for (int i = 0; i < 16; i += 2 * h) {
#pragma unroll
            for (int j = i; j < i + h; ++j) {
                float u = a[j];
                float v = a[j + h];
                a[j]     = u + v;
                a[j + h] = u - v;
            }
        }
    }
}

// LDS address map: A(i) = i ^ (((i>>6)&15) << 2).
// BIJECTIVE: the XOR only flips bits 2..5, which don't feed i>>6, so
// i = A ^ (((A>>6)&15)<<2). (Round-2's additive map was non-injective:
// A(964)==A(1024) — that was the correctness bug.)
// Bank analysis (32 banks, per wave):
//  - exchange-1 b128 writes: quad starts uniform over the 8 slots mod 32
//    -> 8 words/bank = structural floor for 256 words -> conflict-free
//  - pass-B b32 r/w: bank = (t&3) + 4*((m&7)^((t>>2)&7)) -> exactly 2-way, free
//  - pass-C b32 reads: bank = (l&31) ^ ((m&7)<<2) -> exactly 2-way, free
#define LDS_WORDS 4096

__global__ __launch_bounds__(TPB) void fwht_rows_kernel(
        const float* __restrict__ x,
        const float* __restrict__ s,
        float* __restrict__ out) {
    __shared__ float lds[LDS_WORDS];

    const int row = blockIdx.x;
    const int t   = threadIdx.x;
    const float* xr  = x   + (size_t)row * FWHT_N;
    float*       orw = out + (size_t)row * FWHT_N;

    float a[16];

    // ---- Pass A: idx bits {0,1,10,11}. Thread t owns idx = 4t + j + 1024k.
    // Per instruction: 64 lanes x 16 B contiguous = 1 KiB (perfectly coalesced).
#pragma unroll
    for (int k = 0; k < 4; ++k) {
        float4 xx = *(const float4*)(xr + 4 * t + 1024 * k);
        float4 ss = *(const float4*)(s  + 4 * t + 1024 * k);
        a[4 * k + 0] = xx.x * ss.x;
        a[4 * k + 1] = xx.y * ss.y;
        a[4 * k + 2] = xx.z * ss.z;
        a[4 * k + 3] = xx.w * ss.w;
    }
    fwht16(a);   // m bits {0,1} = idx bits {0,1}; m bits {2,3} = idx bits {10,11}

    // ---- Exchange 1: four ds_write_b128. j in 0..3 only touches bits 0..1,
    // the XOR only bits 2..5, so A(i+j) = A(i)+j -> quads stay contiguous.
#pragma unroll
    for (int k = 0; k < 4; ++k) {
        int i    = 4 * t + 1024 * k;
        int addr = i ^ (((i >> 6) & 15) << 2);
        *(float4*)(lds + addr) =
            make_float4(a[4 * k + 0], a[4 * k + 1], a[4 * k + 2], a[4 * k + 3]);
    }
    __syncthreads();

    // ---- Pass B: idx bits {2..5}. Thread owns idx = (t&3) + 4m + 64*(t>>2).
    // idx>>6 = t>>2, so A(idx) = 64*(t>>2) + (t&3) + 4*(m ^ ((t>>2)&15)).
    {
        const int w    = t >> 2;
        const int base = 64 * w + (t & 3);
        const int swz  = w & 15;
#pragma unroll
        for (int m = 0; m < 16; ++m) a[m] = lds[base + 4 * (m ^ swz)];
        fwht16(a);
        // Same cells, same thread: no barrier between this read and write.
#pragma unroll
        for (int m = 0; m < 16; ++m) lds[base + 4 * (m ^ swz)] = a[m];
    }
    __syncthreads();

    // ---- Pass C: idx bits {6..9}. Thread owns idx = (t&63) + 64m + 1024*(t>>6).
    // (idx>>6)&15 = m, so A(idx) = 1024*(t>>6) + 64m + ((t&63) ^ (m<<2)).
    {
        const int hi = 1024 * (t >> 6);
        const int lo = t & 63;
#pragma unroll
        for (int m = 0; m < 16; ++m) a[m] = lds[hi + 64 * m + (lo ^ (m << 2))];
    }
    fwht16(a);

    // ---- Scale and store: out[(t&63) + 64m + 1024*(t>>6)].
    // Per instruction: 256 B contiguous per wave; full lines across the block.
    const float scale = 0.015625f;  // 1/sqrt(4096)
    const int baseO = (t & 63) + 1024 * (t >> 6);
#pragma unroll
    for (int m = 0; m < 16; ++m) {
        orw[baseO + 64 * m] = a[m] * scale;
    }
}

extern "C" void kernel_launch(void* const* d_in, const int* in_sizes, int n_in,
                              void* d_out, int out_size, void* d_ws, size_t ws_size,
                              hipStream_t stream) {
    const float* x = (const float*)d_in[0];
    const float* s = (const float*)d_in[1];
    float* out = (float*)d_out;
    const int rows = in_sizes[0] / FWHT_N;  // 16384
    fwht_rows_kernel<<<rows, TPB, 0, stream>>>(x, s, out);
}